// Round 2
// baseline (3446.278 us; speedup 1.0000x reference)
//
#include <hip/hip_runtime.h>
#include <math.h>

namespace {

constexpr int B = 32, N = 125, D = 256, H = 8, HD = 32, FF = 1024,
              E = 5, V = 32000, HID = 128, S = 128, MAXPOS = 512;
constexpr float EPS = 1e-12f;
constexpr float THRESH = 0.7f;

__device__ __forceinline__ float block_reduce_sum_256(float x, float* red) {
  int t = threadIdx.x;
  red[t] = x;
  __syncthreads();
#pragma unroll
  for (int s = 128; s > 0; s >>= 1) {
    if (t < s) red[t] += red[t + s];
    __syncthreads();
  }
  float r = red[0];
  __syncthreads();
  return r;
}

__device__ __forceinline__ float gelu_exact(float x) {
  return 0.5f * x * (1.f + erff(x * 0.70710678118654752f));
}

// ---------------- router ----------------
__global__ __launch_bounds__(HID) void router1_kernel(
    const float* __restrict__ h_t, const float* __restrict__ e_task,
    const float* __restrict__ e_layout, const float* __restrict__ W1,
    const float* __restrict__ b1, const float* __restrict__ W2,
    const float* __restrict__ b2, const float* __restrict__ hintW,
    const float* __restrict__ hintb, float* __restrict__ gp_ws,
    float* __restrict__ gp_out) {
  int b = blockIdx.x;
  int t = threadIdx.x;
  float acc = b1[t];
  const float* rows[3] = {h_t + b * D, e_task + b * D, e_layout + b * D};
  for (int seg = 0; seg < 3; ++seg) {
    const float* r = rows[seg];
    const float* w = W1 + (size_t)seg * D * HID;
    for (int i = 0; i < D; ++i) acc += r[i] * w[i * HID + t];
  }
  __shared__ float hid[HID];
  __shared__ float logits[E];
  hid[t] = fmaxf(acc, 0.f);
  __syncthreads();
  if (t < E) {
    float l = b2[t] + hintb[t];
    for (int hh = 0; hh < HID; ++hh) l += hid[hh] * W2[hh * E + t];
    const float* el = e_layout + b * D;
    for (int dd = 0; dd < D; ++dd) l += el[dd] * hintW[dd * E + t];
    logits[t] = l;
  }
  __syncthreads();
  if (t == 0) {
    float mx = logits[0];
    for (int e2 = 1; e2 < E; ++e2) mx = fmaxf(mx, logits[e2]);
    float p[E];
    float se = 0.f;
    for (int e2 = 0; e2 < E; ++e2) {
      p[e2] = expf(logits[e2] - mx);
      se += p[e2];
    }
    float inv = 1.f / se;
    for (int e2 = 0; e2 < E; ++e2) {
      float pe = p[e2] * inv;
      gp_ws[b * E + e2] = pe;
      gp_out[b * E + e2] = pe;
    }
  }
}

__global__ __launch_bounds__(64) void router2_kernel(
    const float* __restrict__ gp, const int* __restrict__ topk_ptr,
    float* __restrict__ comb) {
  __shared__ int allk1;
  int t = threadIdx.x;
  if (t == 0) allk1 = 1;
  __syncthreads();
  float p[E];
  if (t < B) {
    float mx = 0.f;
    for (int e2 = 0; e2 < E; ++e2) {
      p[e2] = gp[t * E + e2];
      mx = fmaxf(mx, p[e2]);
    }
    if (!(mx > THRESH)) allk1 = 0;  // benign race: all writers store 0
  }
  __syncthreads();
  int k1 = allk1;
  if (t < B) {
    for (int e2 = 0; e2 < E; ++e2) comb[t * E + e2] = 0.f;
    int tk = *topk_ptr;
    if (tk > E) tk = E;
    float q[E];
    for (int e2 = 0; e2 < E; ++e2) q[e2] = p[e2];
    for (int kk = 0; kk < tk; ++kk) {
      int bi = 0;
      float bv = q[0];
      for (int e2 = 1; e2 < E; ++e2)
        if (q[e2] > bv) { bv = q[e2]; bi = e2; }
      float w = (kk == 0) ? bv : (k1 ? 0.f : bv);
      comb[t * E + bi] += w;
      q[bi] = -1.f;
    }
  }
}

// ---------------- embedding + LN ----------------
__global__ __launch_bounds__(256) void embed_ln_kernel(
    const float* __restrict__ h_t, const float* __restrict__ e_task,
    const float* __restrict__ e_layout, const float* __restrict__ tok,
    const float* __restrict__ pos_e, const float* __restrict__ typ_e,
    const float* __restrict__ g, const float* __restrict__ bb,
    float* __restrict__ outp, const float* __restrict__ comb, int e) {
  int bs = blockIdx.x;
  int b = bs >> 7, s = bs & 127;
  if (comb[b * E + e] == 0.f) return;
  int d = threadIdx.x;
  float x;
  if (s >= 3)
    x = tok[((size_t)(b * N + (s - 3))) * D + d];
  else if (s == 0)
    x = h_t[b * D + d];
  else if (s == 1)
    x = e_task[b * D + d];
  else
    x = e_layout[b * D + d];
  x += pos_e[(size_t)s * D + d] + typ_e[d];
  __shared__ float red[256];
  float m = block_reduce_sum_256(x, red) * (1.f / D);
  float xm = x - m;
  float v2 = block_reduce_sum_256(xm * xm, red) * (1.f / D);
  outp[(size_t)bs * D + d] = xm * rsqrtf(v2 + EPS) * g[d] + bb[d];
}

// ---------------- residual add + LN ----------------
__global__ __launch_bounds__(256) void add_ln_kernel(
    const float* __restrict__ A, const float* __restrict__ R,
    const float* __restrict__ g, const float* __restrict__ bb,
    float* __restrict__ outp, const float* __restrict__ comb, int e) {
  int bs = blockIdx.x;
  int b = bs >> 7;
  if (comb[b * E + e] == 0.f) return;
  int d = threadIdx.x;
  float x = A[(size_t)bs * D + d] + R[(size_t)bs * D + d];
  __shared__ float red[256];
  float m = block_reduce_sum_256(x, red) * (1.f / D);
  float xm = x - m;
  float v2 = block_reduce_sum_256(xm * xm, red) * (1.f / D);
  outp[(size_t)bs * D + d] = xm * rsqrtf(v2 + EPS) * g[d] + bb[d];
}

// ---------------- attention: one block per (b,h) ----------------
__global__ __launch_bounds__(128) void attn_kernel(
    const float* __restrict__ Q, const float* __restrict__ K,
    const float* __restrict__ Vv, float* __restrict__ C,
    const float* __restrict__ comb, int e) {
  int bh = blockIdx.x;
  int b = bh >> 3, h = bh & 7;
  if (comb[b * E + e] == 0.f) return;
  __shared__ float Ks[S][HD + 1];
  __shared__ float Vs[S][HD + 1];
  __shared__ float qs[HD];
  __shared__ float red[128];
  __shared__ float attnw[128];
  int t = threadIdx.x;
  const float* kb = K + ((size_t)(b * S)) * D + h * HD;
  const float* vb = Vv + ((size_t)(b * S)) * D + h * HD;
#pragma unroll
  for (int d = 0; d < HD; d += 4) {
    float4 k4 = *reinterpret_cast<const float4*>(kb + (size_t)t * D + d);
    Ks[t][d] = k4.x; Ks[t][d + 1] = k4.y; Ks[t][d + 2] = k4.z; Ks[t][d + 3] = k4.w;
    float4 v4 = *reinterpret_cast<const float4*>(vb + (size_t)t * D + d);
    Vs[t][d] = v4.x; Vs[t][d + 1] = v4.y; Vs[t][d + 2] = v4.z; Vs[t][d + 3] = v4.w;
  }
  __syncthreads();
  const float scale = 0.17677669529663687f;  // 1/sqrt(32)
  for (int qi = 0; qi < S; ++qi) {
    if (t < HD) qs[t] = Q[((size_t)(b * S + qi)) * D + h * HD + t];
    __syncthreads();
    float sc = 0.f;
#pragma unroll
    for (int d = 0; d < HD; ++d) sc += qs[d] * Ks[t][d];
    sc *= scale;
    red[t] = sc;
    __syncthreads();
#pragma unroll
    for (int s2 = 64; s2 > 0; s2 >>= 1) {
      if (t < s2) red[t] = fmaxf(red[t], red[t + s2]);
      __syncthreads();
    }
    float mx = red[0];
    __syncthreads();
    float ex = expf(sc - mx);
    red[t] = ex;
    __syncthreads();
#pragma unroll
    for (int s2 = 64; s2 > 0; s2 >>= 1) {
      if (t < s2) red[t] += red[t + s2];
      __syncthreads();
    }
    float inv = 1.f / red[0];
    __syncthreads();
    attnw[t] = ex * inv;
    __syncthreads();
    int d = t & (HD - 1);
    int grp = t >> 5;
    float part = 0.f;
#pragma unroll
    for (int j = 0; j < 32; ++j) part += attnw[grp * 32 + j] * Vs[grp * 32 + j][d];
    red[t] = part;
    __syncthreads();
    if (t < HD) {
      float cx = red[t] + red[t + 32] + red[t + 64] + red[t + 96];
      C[((size_t)(b * S + qi)) * D + h * HD + t] = cx;
    }
    __syncthreads();
  }
}

// ---------------- generic fp32 GEMM: out[M,Nc] = A[M,K] @ W[K,Nc] + bias ----
// ACT: 0 = none, 1 = exact GELU. comb (optional): per-batch-row expert skip.
template <int ACT>
__global__ __launch_bounds__(256) void gemm_kernel(
    const float* __restrict__ A, const float* __restrict__ W,
    const float* __restrict__ bias, float* __restrict__ outp, int M, int K,
    int Nc, const float* __restrict__ comb, int e) {
  int row0 = blockIdx.y * 64;
  int col0 = blockIdx.x * 64;
  if (comb) {
    int b = row0 / S;  // 64-row tile never crosses a batch row (S=128)
    if (comb[b * E + e] == 0.f) return;
  }
  __shared__ float As[16][64];
  __shared__ float Bs[16][64];
  int t = threadIdx.x;
  int tx = t & 15, ty = t >> 4;
  int arow = t >> 2, ak = (t & 3) << 2;
  int brow = t >> 4, bn = (t & 15) << 2;
  float acc[4][4] = {};
  for (int k0 = 0; k0 < K; k0 += 16) {
    float4 a4 = *reinterpret_cast<const float4*>(
        A + (size_t)(row0 + arow) * K + k0 + ak);
    As[ak + 0][arow] = a4.x;
    As[ak + 1][arow] = a4.y;
    As[ak + 2][arow] = a4.z;
    As[ak + 3][arow] = a4.w;
    float4 b4 = *reinterpret_cast<const float4*>(
        W + (size_t)(k0 + brow) * Nc + col0 + bn);
    *reinterpret_cast<float4*>(&Bs[brow][bn]) = b4;
    __syncthreads();
#pragma unroll
    for (int kk = 0; kk < 16; ++kk) {
      float4 av = *reinterpret_cast<const float4*>(&As[kk][ty << 2]);
      float4 bv = *reinterpret_cast<const float4*>(&Bs[kk][tx << 2]);
      acc[0][0] += av.x * bv.x; acc[0][1] += av.x * bv.y;
      acc[0][2] += av.x * bv.z; acc[0][3] += av.x * bv.w;
      acc[1][0] += av.y * bv.x; acc[1][1] += av.y * bv.y;
      acc[1][2] += av.y * bv.z; acc[1][3] += av.y * bv.w;
      acc[2][0] += av.z * bv.x; acc[2][1] += av.z * bv.y;
      acc[2][2] += av.z * bv.z; acc[2][3] += av.z * bv.w;
      acc[3][0] += av.w * bv.x; acc[3][1] += av.w * bv.y;
      acc[3][2] += av.w * bv.z; acc[3][3] += av.w * bv.w;
    }
    __syncthreads();
  }
  const float* pb = bias + col0 + (tx << 2);
  float bx = pb[0], by = pb[1], bz = pb[2], bw = pb[3];
#pragma unroll
  for (int i = 0; i < 4; ++i) {
    int r = row0 + (ty << 2) + i;
    float4 o;
    o.x = acc[i][0] + bx;
    o.y = acc[i][1] + by;
    o.z = acc[i][2] + bz;
    o.w = acc[i][3] + bw;
    if (ACT == 1) {
      o.x = gelu_exact(o.x); o.y = gelu_exact(o.y);
      o.z = gelu_exact(o.z); o.w = gelu_exact(o.w);
    }
    *reinterpret_cast<float4*>(outp + (size_t)r * Nc + col0 + (tx << 2)) = o;
  }
}

// ---------------- z accumulate / zero ----------------
__global__ __launch_bounds__(256) void zero_kernel(float* __restrict__ p) {
  p[(size_t)blockIdx.x * 256 + threadIdx.x] = 0.f;
}

__global__ __launch_bounds__(256) void accum_z_kernel(
    float* __restrict__ z, const float* __restrict__ h2,
    const float* __restrict__ comb, int e) {
  size_t i = (size_t)blockIdx.x * 256 + threadIdx.x;
  int b = (int)(i / ((size_t)S * D));
  float c = comb[b * E + e];
  if (c != 0.f) z[i] += c * h2[i];
}

}  // namespace

extern "C" void kernel_launch(void* const* d_in, const int* in_sizes, int n_in,
                              void* d_out, int out_size, void* d_ws,
                              size_t ws_size, hipStream_t stream) {
  const float* h_t = (const float*)d_in[0];
  const float* e_task = (const float*)d_in[1];
  const float* e_layout = (const float*)d_in[2];
  const float* tok = (const float*)d_in[3];
  const float* rW1 = (const float*)d_in[4];
  const float* rb1 = (const float*)d_in[5];
  const float* rW2 = (const float*)d_in[6];
  const float* rb2 = (const float*)d_in[7];
  const float* hW = (const float*)d_in[8];
  const float* hb = (const float*)d_in[9];
  const float* pos = (const float*)d_in[10];
  const float* typ = (const float*)d_in[11];
  const float* g0 = (const float*)d_in[12];
  const float* b0 = (const float*)d_in[13];
  const float* Wq = (const float*)d_in[14];
  const float* bq = (const float*)d_in[15];
  const float* Wk = (const float*)d_in[16];
  const float* bk = (const float*)d_in[17];
  const float* Wv = (const float*)d_in[18];
  const float* bv = (const float*)d_in[19];
  const float* Wo = (const float*)d_in[20];
  const float* bo = (const float*)d_in[21];
  const float* g1 = (const float*)d_in[22];
  const float* b1 = (const float*)d_in[23];
  const float* Wf1 = (const float*)d_in[24];
  const float* bf1 = (const float*)d_in[25];
  const float* Wf2 = (const float*)d_in[26];
  const float* bf2 = (const float*)d_in[27];
  const float* g2 = (const float*)d_in[28];
  const float* b2 = (const float*)d_in[29];
  const float* headW = (const float*)d_in[30];
  const float* headb = (const float*)d_in[31];
  const int* topk = (const int*)d_in[32];

  float* out = (float*)d_out;
  float* gp_out = out + (size_t)B * S * V;  // gate_probs tail of d_out

  // Big per-expert scratch lives in the logits region of d_out (fully
  // overwritten by the final head GEMM; gate_probs tail is never touched).
  float* h0 = out;                       // [B*S, D]
  float* qb = h0 + (size_t)B * S * D;    // [B*S, D]
  float* kb = qb + (size_t)B * S * D;    // [B*S, D]
  float* vb = kb + (size_t)B * S * D;    // [B*S, D]
  float* ctxb = vb + (size_t)B * S * D;  // [B*S, D]
  float* fb = ctxb + (size_t)B * S * D;  // [B*S, FF]

  // Small state in d_ws (z must survive the head GEMM's overwrite of d_out).
  float* comb = (float*)d_ws;        // [B,E]   (256 floats padded)
  float* gp = comb + 256;            // [B,E]   (256 floats padded)
  float* zb = gp + 256;              // [B*S, D]

  router1_kernel<<<B, HID, 0, stream>>>(h_t, e_task, e_layout, rW1, rb1, rW2,
                                        rb2, hW, hb, gp, gp_out);
  router2_kernel<<<1, 64, 0, stream>>>(gp, topk, comb);
  zero_kernel<<<(B * S * D) / 256, 256, 0, stream>>>(zb);

  dim3 gD(D / 64, (B * S) / 64);
  dim3 gFF(FF / 64, (B * S) / 64);
  for (int e = 0; e < E; ++e) {
    embed_ln_kernel<<<B * S, D, 0, stream>>>(
        h_t, e_task, e_layout, tok, pos + (size_t)e * MAXPOS * D,
        typ + (size_t)e * D, g0 + (size_t)e * D, b0 + (size_t)e * D, h0, comb,
        e);
    gemm_kernel<0><<<gD, 256, 0, stream>>>(h0, Wq + (size_t)e * D * D,
                                           bq + (size_t)e * D, qb, B * S, D, D,
                                           comb, e);
    gemm_kernel<0><<<gD, 256, 0, stream>>>(h0, Wk + (size_t)e * D * D,
                                           bk + (size_t)e * D, kb, B * S, D, D,
                                           comb, e);
    gemm_kernel<0><<<gD, 256, 0, stream>>>(h0, Wv + (size_t)e * D * D,
                                           bv + (size_t)e * D, vb, B * S, D, D,
                                           comb, e);
    attn_kernel<<<B * H, 128, 0, stream>>>(qb, kb, vb, ctxb, comb, e);
    gemm_kernel<0><<<gD, 256, 0, stream>>>(ctxb, Wo + (size_t)e * D * D,
                                           bo + (size_t)e * D, qb, B * S, D, D,
                                           comb, e);
    add_ln_kernel<<<B * S, D, 0, stream>>>(h0, qb, g1 + (size_t)e * D,
                                           b1 + (size_t)e * D, kb, comb, e);
    gemm_kernel<1><<<gFF, 256, 0, stream>>>(kb, Wf1 + (size_t)e * D * FF,
                                            bf1 + (size_t)e * FF, fb, B * S, D,
                                            FF, comb, e);
    gemm_kernel<0><<<gD, 256, 0, stream>>>(fb, Wf2 + (size_t)e * FF * D,
                                           bf2 + (size_t)e * D, vb, B * S, FF,
                                           D, comb, e);
    add_ln_kernel<<<B * S, D, 0, stream>>>(kb, vb, g2 + (size_t)e * D,
                                           b2 + (size_t)e * D, h0, comb, e);
    accum_z_kernel<<<(B * S * D) / 256, 256, 0, stream>>>(zb, h0, comb, e);
  }

  dim3 gHead(V / 64, (B * S) / 64);
  gemm_kernel<0><<<gHead, 256, 0, stream>>>(zb, headW, headb, out, B * S, D, V,
                                            nullptr, 0);
  (void)in_sizes; (void)n_in; (void)out_size; (void)ws_size;
}

// Round 3
// 1302.550 us; speedup vs baseline: 2.6458x; 2.6458x over previous
//
#include <hip/hip_runtime.h>
#include <hip/hip_bf16.h>
#include <math.h>

namespace {

constexpr int B = 32, N = 125, D = 256, H = 8, HD = 32, FF = 1024,
              E = 5, V = 32000, HID = 128, S = 128, MAXPOS = 512;
constexpr float EPS = 1e-12f;
constexpr float THRESH = 0.7f;

typedef __attribute__((ext_vector_type(4))) float f32x4;
typedef __attribute__((ext_vector_type(8))) short short8v;

__device__ __forceinline__ short f2bf(float f) {
  __hip_bfloat16 h = __float2bfloat16(f);  // RNE
  short s;
  __builtin_memcpy(&s, &h, 2);
  return s;
}

__device__ __forceinline__ float gelu_exact(float x) {
  return 0.5f * x * (1.f + erff(x * 0.70710678118654752f));
}

__device__ __forceinline__ float wave_sum64(float v) {
#pragma unroll
  for (int off = 32; off > 0; off >>= 1) v += __shfl_xor(v, off);
  return v;
}

// ---------------- router ----------------
__global__ __launch_bounds__(HID) void router1_kernel(
    const float* __restrict__ h_t, const float* __restrict__ e_task,
    const float* __restrict__ e_layout, const float* __restrict__ W1,
    const float* __restrict__ b1, const float* __restrict__ W2,
    const float* __restrict__ b2, const float* __restrict__ hintW,
    const float* __restrict__ hintb, float* __restrict__ gp_ws,
    float* __restrict__ gp_out) {
  int b = blockIdx.x;
  int t = threadIdx.x;
  float acc = b1[t];
  const float* rows[3] = {h_t + b * D, e_task + b * D, e_layout + b * D};
  for (int seg = 0; seg < 3; ++seg) {
    const float* r = rows[seg];
    const float* w = W1 + (size_t)seg * D * HID;
    for (int i = 0; i < D; ++i) acc += r[i] * w[i * HID + t];
  }
  __shared__ float hid[HID];
  __shared__ float logits[E];
  hid[t] = fmaxf(acc, 0.f);
  __syncthreads();
  if (t < E) {
    float l = b2[t] + hintb[t];
    for (int hh = 0; hh < HID; ++hh) l += hid[hh] * W2[hh * E + t];
    const float* el = e_layout + b * D;
    for (int dd = 0; dd < D; ++dd) l += el[dd] * hintW[dd * E + t];
    logits[t] = l;
  }
  __syncthreads();
  if (t == 0) {
    float mx = logits[0];
    for (int e2 = 1; e2 < E; ++e2) mx = fmaxf(mx, logits[e2]);
    float p[E];
    float se = 0.f;
    for (int e2 = 0; e2 < E; ++e2) {
      p[e2] = expf(logits[e2] - mx);
      se += p[e2];
    }
    float inv = 1.f / se;
    for (int e2 = 0; e2 < E; ++e2) {
      float pe = p[e2] * inv;
      gp_ws[b * E + e2] = pe;
      gp_out[b * E + e2] = pe;
    }
  }
}

__global__ __launch_bounds__(64) void router2_kernel(
    const float* __restrict__ gp, const int* __restrict__ topk_ptr,
    float* __restrict__ comb) {
  __shared__ int allk1;
  int t = threadIdx.x;
  if (t == 0) allk1 = 1;
  __syncthreads();
  float p[E];
  if (t < B) {
    float mx = 0.f;
    for (int e2 = 0; e2 < E; ++e2) {
      p[e2] = gp[t * E + e2];
      mx = fmaxf(mx, p[e2]);
    }
    if (!(mx > THRESH)) allk1 = 0;  // benign race: all writers store 0
  }
  __syncthreads();
  int k1 = allk1;
  if (t < B) {
    for (int e2 = 0; e2 < E; ++e2) comb[t * E + e2] = 0.f;
    int tk = *topk_ptr;
    if (tk > E) tk = E;
    float q[E];
    for (int e2 = 0; e2 < E; ++e2) q[e2] = p[e2];
    for (int kk = 0; kk < tk; ++kk) {
      int bi = 0;
      float bv = q[0];
      for (int e2 = 1; e2 < E; ++e2)
        if (q[e2] > bv) { bv = q[e2]; bi = e2; }
      float w = (kk == 0) ? bv : (k1 ? 0.f : bv);
      comb[t * E + bi] += w;
      q[bi] = -1.f;
    }
  }
}

// ---------------- embedding + LN (wave per row) ----------------
__global__ __launch_bounds__(256) void embed_ln_w(
    const float* __restrict__ h_t, const float* __restrict__ e_task,
    const float* __restrict__ e_layout, const float* __restrict__ tok,
    const float* __restrict__ pos_e, const float* __restrict__ typ_e,
    const float* __restrict__ g, const float* __restrict__ bb,
    float* __restrict__ outp, const float* __restrict__ comb, int e) {
  int t = threadIdx.x, lane = t & 63, w = t >> 6;
  int row = blockIdx.x * 4 + w;
  int b = row >> 7, s = row & 127;
  if (comb[b * E + e] == 0.f) return;
  int d0 = lane * 4;
  const float* src = (s >= 3) ? tok + ((size_t)(b * N + s - 3)) * D
                   : (s == 0) ? h_t + (size_t)b * D
                   : (s == 1) ? e_task + (size_t)b * D
                              : e_layout + (size_t)b * D;
  float4 x = *reinterpret_cast<const float4*>(src + d0);
  float4 pe = *reinterpret_cast<const float4*>(pos_e + (size_t)s * D + d0);
  float4 te = *reinterpret_cast<const float4*>(typ_e + d0);
  x.x += pe.x + te.x; x.y += pe.y + te.y;
  x.z += pe.z + te.z; x.w += pe.w + te.w;
  float mean = wave_sum64(x.x + x.y + x.z + x.w) * (1.f / D);
  float4 xm = {x.x - mean, x.y - mean, x.z - mean, x.w - mean};
  float vv = wave_sum64(xm.x * xm.x + xm.y * xm.y + xm.z * xm.z + xm.w * xm.w);
  float rs = rsqrtf(vv * (1.f / D) + EPS);
  float4 g4 = *reinterpret_cast<const float4*>(g + d0);
  float4 b4 = *reinterpret_cast<const float4*>(bb + d0);
  float4 o = {xm.x * rs * g4.x + b4.x, xm.y * rs * g4.y + b4.y,
              xm.z * rs * g4.z + b4.z, xm.w * rs * g4.w + b4.w};
  *reinterpret_cast<float4*>(outp + (size_t)row * D + d0) = o;
}

// ---------------- add + LN (wave per row); ACC: z += c * ln(...) -----------
template <int ACC>
__global__ __launch_bounds__(256) void add_ln_w(
    const float* __restrict__ A, const float* __restrict__ R,
    const float* __restrict__ g, const float* __restrict__ bb,
    float* __restrict__ outp, float* __restrict__ zp,
    const float* __restrict__ comb, int e) {
  int t = threadIdx.x, lane = t & 63, w = t >> 6;
  int row = blockIdx.x * 4 + w;
  int b = row >> 7;
  float c = comb[b * E + e];
  if (c == 0.f) return;
  int d0 = lane * 4;
  float4 a4 = *reinterpret_cast<const float4*>(A + (size_t)row * D + d0);
  float4 r4 = *reinterpret_cast<const float4*>(R + (size_t)row * D + d0);
  float4 x = {a4.x + r4.x, a4.y + r4.y, a4.z + r4.z, a4.w + r4.w};
  float mean = wave_sum64(x.x + x.y + x.z + x.w) * (1.f / D);
  float4 xm = {x.x - mean, x.y - mean, x.z - mean, x.w - mean};
  float vv = wave_sum64(xm.x * xm.x + xm.y * xm.y + xm.z * xm.z + xm.w * xm.w);
  float rs = rsqrtf(vv * (1.f / D) + EPS);
  float4 g4 = *reinterpret_cast<const float4*>(g + d0);
  float4 b4 = *reinterpret_cast<const float4*>(bb + d0);
  float4 o = {xm.x * rs * g4.x + b4.x, xm.y * rs * g4.y + b4.y,
              xm.z * rs * g4.z + b4.z, xm.w * rs * g4.w + b4.w};
  if (ACC) {
    float4 z4 = *reinterpret_cast<float4*>(zp + (size_t)row * D + d0);
    z4.x += c * o.x; z4.y += c * o.y; z4.z += c * o.z; z4.w += c * o.w;
    *reinterpret_cast<float4*>(zp + (size_t)row * D + d0) = z4;
  } else {
    *reinterpret_cast<float4*>(outp + (size_t)row * D + d0) = o;
  }
}

// ---------------- attention: thread per query row ----------------
__global__ __launch_bounds__(128) void attn2_kernel(
    const float* __restrict__ Q, const float* __restrict__ K,
    const float* __restrict__ Vv, float* __restrict__ C,
    const float* __restrict__ comb, int e) {
  int bh = blockIdx.x;
  int b = bh >> 3, h = bh & 7;
  if (comb[b * E + e] == 0.f) return;
  __shared__ float Ks[S][36];  // 36 floats -> 144B rows, 16B aligned
  __shared__ float Vs[S][36];
  int t = threadIdx.x;
  const float* kb = K + ((size_t)(b * S + t)) * D + h * HD;
  const float* vb = Vv + ((size_t)(b * S + t)) * D + h * HD;
#pragma unroll
  for (int d = 0; d < HD; d += 4) {
    *reinterpret_cast<float4*>(&Ks[t][d]) =
        *reinterpret_cast<const float4*>(kb + d);
    *reinterpret_cast<float4*>(&Vs[t][d]) =
        *reinterpret_cast<const float4*>(vb + d);
  }
  float4 qv[8];
  const float* qp = Q + ((size_t)(b * S + t)) * D + h * HD;
#pragma unroll
  for (int j = 0; j < 8; ++j)
    qv[j] = *reinterpret_cast<const float4*>(qp + j * 4);
  __syncthreads();
  const float scale = 0.17677669529663687f;  // 1/sqrt(32)
  float mx = -1e30f;
  for (int k = 0; k < S; ++k) {
    float s = 0.f;
#pragma unroll
    for (int j = 0; j < 8; ++j) {
      float4 k4 = *reinterpret_cast<const float4*>(&Ks[k][j * 4]);
      s += qv[j].x * k4.x + qv[j].y * k4.y + qv[j].z * k4.z + qv[j].w * k4.w;
    }
    mx = fmaxf(mx, s * scale);
  }
  float se = 0.f;
  float4 cx[8];
#pragma unroll
  for (int j = 0; j < 8; ++j) cx[j] = {0.f, 0.f, 0.f, 0.f};
  for (int k = 0; k < S; ++k) {
    float s = 0.f;
#pragma unroll
    for (int j = 0; j < 8; ++j) {
      float4 k4 = *reinterpret_cast<const float4*>(&Ks[k][j * 4]);
      s += qv[j].x * k4.x + qv[j].y * k4.y + qv[j].z * k4.z + qv[j].w * k4.w;
    }
    float p = expf(s * scale - mx);
    se += p;
#pragma unroll
    for (int j = 0; j < 8; ++j) {
      float4 v4 = *reinterpret_cast<const float4*>(&Vs[k][j * 4]);
      cx[j].x += p * v4.x; cx[j].y += p * v4.y;
      cx[j].z += p * v4.z; cx[j].w += p * v4.w;
    }
  }
  float inv = 1.f / se;
  float* cp = C + ((size_t)(b * S + t)) * D + h * HD;
#pragma unroll
  for (int j = 0; j < 8; ++j) {
    float4 o = {cx[j].x * inv, cx[j].y * inv, cx[j].z * inv, cx[j].w * inv};
    *reinterpret_cast<float4*>(cp + j * 4) = o;
  }
}

// ---------------- bf16 MFMA GEMM: out[4096,Nc] = A[4096,K] @ W[K,Nc] + bias
// fp32 in/out, on-the-fly bf16 conversion. 128x128 tile, BK=32, 4 waves.
template <int ACT, int K, int Nc>
__global__ __launch_bounds__(256) void gemm_mfma(
    const float* __restrict__ Ag, const float* __restrict__ Wg,
    const float* __restrict__ bias, float* __restrict__ outp,
    const float* __restrict__ comb, int e) {
  const int row0 = blockIdx.y * 128;
  const int col0 = blockIdx.x * 128;
  if (comb) {
    int b = row0 >> 7;  // BM = 128 = S, so row tile == batch row
    if (comb[b * E + e] == 0.f) return;
  }
  // padded stride 40 bf16 (80B): frag ds_read_b128 lands 2-way on banks (free)
  __shared__ short Al[128 * 40];
  __shared__ short Bl[128 * 40];
  const int t = threadIdx.x;
  const int lane = t & 63;
  const int w = t >> 6;
  const int wr = w >> 1, wc = w & 1;
  const int lrow = lane & 15;
  const int lkoff = (lane >> 4) * 8;  // bf16 units

  f32x4 acc[4][4];
#pragma unroll
  for (int m = 0; m < 4; ++m)
#pragma unroll
    for (int n = 0; n < 4; ++n) acc[m][n] = (f32x4){0.f, 0.f, 0.f, 0.f};

  const int colB = t >> 1, kh = (t & 1) * 16;
  for (int k0 = 0; k0 < K; k0 += 32) {
    // stage A: 128x32 fp32 -> bf16, [row][k] stride 40
#pragma unroll
    for (int j = 0; j < 4; ++j) {
      int id = t + 256 * j;
      int row = id >> 3, s4 = id & 7;
      float4 a4 = *reinterpret_cast<const float4*>(
          Ag + (size_t)(row0 + row) * K + k0 + s4 * 4);
      short4 p;
      p.x = f2bf(a4.x); p.y = f2bf(a4.y); p.z = f2bf(a4.z); p.w = f2bf(a4.w);
      *reinterpret_cast<short4*>(&Al[row * 40 + s4 * 4]) = p;
    }
    // stage B transposed: W[k0..k0+32][col0..col0+128] -> Bl[col][k] stride 40
    {
      const float* wp = Wg + (size_t)(k0 + kh) * Nc + (col0 + colB);
      short8v v0, v1;
#pragma unroll
      for (int kk = 0; kk < 8; ++kk) v0[kk] = f2bf(wp[(size_t)kk * Nc]);
#pragma unroll
      for (int kk = 0; kk < 8; ++kk) v1[kk] = f2bf(wp[(size_t)(kk + 8) * Nc]);
      *reinterpret_cast<short8v*>(&Bl[colB * 40 + kh]) = v0;
      *reinterpret_cast<short8v*>(&Bl[colB * 40 + kh + 8]) = v1;
    }
    __syncthreads();
    short8v af[4], bfv[4];
#pragma unroll
    for (int m = 0; m < 4; ++m)
      af[m] = *reinterpret_cast<const short8v*>(
          &Al[(wr * 64 + m * 16 + lrow) * 40 + lkoff]);
#pragma unroll
    for (int n = 0; n < 4; ++n)
      bfv[n] = *reinterpret_cast<const short8v*>(
          &Bl[(wc * 64 + n * 16 + lrow) * 40 + lkoff]);
#pragma unroll
    for (int m = 0; m < 4; ++m)
#pragma unroll
      for (int n = 0; n < 4; ++n)
        acc[m][n] = __builtin_amdgcn_mfma_f32_16x16x32_bf16(
            af[m], bfv[n], acc[m][n], 0, 0, 0);
    __syncthreads();
  }
  // epilogue: C row = (lane>>4)*4 + reg, col = lane&15   [m89 layout]
#pragma unroll
  for (int n = 0; n < 4; ++n) {
    int col = col0 + wc * 64 + n * 16 + lrow;
    float bc = bias[col];
#pragma unroll
    for (int m = 0; m < 4; ++m) {
      int rbase = row0 + wr * 64 + m * 16 + (lane >> 4) * 4;
      f32x4 v = acc[m][n];
#pragma unroll
      for (int r = 0; r < 4; ++r) {
        float o = v[r] + bc;
        if (ACT == 1) o = gelu_exact(o);
        outp[(size_t)(rbase + r) * Nc + col] = o;
      }
    }
  }
}

__global__ __launch_bounds__(256) void zero_kernel(float* __restrict__ p) {
  p[(size_t)blockIdx.x * 256 + threadIdx.x] = 0.f;
}

}  // namespace

extern "C" void kernel_launch(void* const* d_in, const int* in_sizes, int n_in,
                              void* d_out, int out_size, void* d_ws,
                              size_t ws_size, hipStream_t stream) {
  const float* h_t = (const float*)d_in[0];
  const float* e_task = (const float*)d_in[1];
  const float* e_layout = (const float*)d_in[2];
  const float* tok = (const float*)d_in[3];
  const float* rW1 = (const float*)d_in[4];
  const float* rb1 = (const float*)d_in[5];
  const float* rW2 = (const float*)d_in[6];
  const float* rb2 = (const float*)d_in[7];
  const float* hW = (const float*)d_in[8];
  const float* hb = (const float*)d_in[9];
  const float* pos = (const float*)d_in[10];
  const float* typ = (const float*)d_in[11];
  const float* g0 = (const float*)d_in[12];
  const float* b0 = (const float*)d_in[13];
  const float* Wq = (const float*)d_in[14];
  const float* bq = (const float*)d_in[15];
  const float* Wk = (const float*)d_in[16];
  const float* bk = (const float*)d_in[17];
  const float* Wv = (const float*)d_in[18];
  const float* bv = (const float*)d_in[19];
  const float* Wo = (const float*)d_in[20];
  const float* bo = (const float*)d_in[21];
  const float* g1 = (const float*)d_in[22];
  const float* b1 = (const float*)d_in[23];
  const float* Wf1 = (const float*)d_in[24];
  const float* bf1 = (const float*)d_in[25];
  const float* Wf2 = (const float*)d_in[26];
  const float* bf2 = (const float*)d_in[27];
  const float* g2 = (const float*)d_in[28];
  const float* b2 = (const float*)d_in[29];
  const float* headW = (const float*)d_in[30];
  const float* headb = (const float*)d_in[31];
  const int* topk = (const int*)d_in[32];

  float* out = (float*)d_out;
  float* gp_out = out + (size_t)B * S * V;  // gate_probs tail of d_out

  // Big per-expert scratch in the logits region of d_out (overwritten by the
  // head GEMM at the end; head GEMM reads only zb (ws) + headW (input)).
  float* h0 = out;                       // [B*S, D]
  float* qb = h0 + (size_t)B * S * D;    // [B*S, D]
  float* kb = qb + (size_t)B * S * D;    // [B*S, D]
  float* vb = kb + (size_t)B * S * D;    // [B*S, D]
  float* ctxb = vb + (size_t)B * S * D;  // [B*S, D]
  float* fb = ctxb + (size_t)B * S * D;  // [B*S, FF]

  float* comb = (float*)d_ws;  // [B,E] padded
  float* gp = comb + 256;      // [B,E] padded
  float* zb = gp + 256;        // [B*S, D] fp32 (survives head GEMM)

  router1_kernel<<<B, HID, 0, stream>>>(h_t, e_task, e_layout, rW1, rb1, rW2,
                                        rb2, hW, hb, gp, gp_out);
  router2_kernel<<<1, 64, 0, stream>>>(gp, topk, comb);
  zero_kernel<<<(B * S * D) / 256, 256, 0, stream>>>(zb);

  dim3 gD(2, 32);    // Nc=256
  dim3 gFF(8, 32);   // Nc=1024
  for (int e = 0; e < E; ++e) {
    embed_ln_w<<<B * S / 4, 256, 0, stream>>>(
        h_t, e_task, e_layout, tok, pos + (size_t)e * MAXPOS * D,
        typ + (size_t)e * D, g0 + (size_t)e * D, b0 + (size_t)e * D, h0, comb,
        e);
    gemm_mfma<0, 256, 256><<<gD, 256, 0, stream>>>(
        h0, Wq + (size_t)e * D * D, bq + (size_t)e * D, qb, comb, e);
    gemm_mfma<0, 256, 256><<<gD, 256, 0, stream>>>(
        h0, Wk + (size_t)e * D * D, bk + (size_t)e * D, kb, comb, e);
    gemm_mfma<0, 256, 256><<<gD, 256, 0, stream>>>(
        h0, Wv + (size_t)e * D * D, bv + (size_t)e * D, vb, comb, e);
    attn2_kernel<<<B * H, 128, 0, stream>>>(qb, kb, vb, ctxb, comb, e);
    gemm_mfma<0, 256, 256><<<gD, 256, 0, stream>>>(
        ctxb, Wo + (size_t)e * D * D, bo + (size_t)e * D, qb, comb, e);
    add_ln_w<0><<<B * S / 4, 256, 0, stream>>>(
        h0, qb, g1 + (size_t)e * D, b1 + (size_t)e * D, kb, nullptr, comb, e);
    gemm_mfma<1, 256, 1024><<<gFF, 256, 0, stream>>>(
        kb, Wf1 + (size_t)e * D * FF, bf1 + (size_t)e * FF, fb, comb, e);
    gemm_mfma<0, 1024, 256><<<gD, 256, 0, stream>>>(
        fb, Wf2 + (size_t)e * FF * D, bf2 + (size_t)e * D, vb, comb, e);
    add_ln_w<1><<<B * S / 4, 256, 0, stream>>>(
        kb, vb, g2 + (size_t)e * D, b2 + (size_t)e * D, nullptr, zb, comb, e);
  }

  dim3 gHead(V / 128, 32);
  gemm_mfma<0, 256, 32000><<<gHead, 256, 0, stream>>>(zb, headW, headb, out,
                                                      nullptr, 0);
  (void)in_sizes; (void)n_in; (void)out_size; (void)ws_size;
}

// Round 4
// 635.182 us; speedup vs baseline: 5.4257x; 2.0507x over previous
//
#include <hip/hip_runtime.h>
#include <hip/hip_bf16.h>
#include <math.h>

namespace {

constexpr int B = 32, N = 125, D = 256, H = 8, HD = 32, FF = 1024,
              E = 5, V = 32000, HID = 128, S = 128, MAXPOS = 512;
constexpr int BSD = B * S * D;     // 1,048,576 floats
constexpr int BSF = B * S * FF;    // 4,194,304 floats
constexpr float EPS = 1e-12f;
constexpr float THRESH = 0.7f;

typedef __attribute__((ext_vector_type(4))) float f32x4;
typedef __attribute__((ext_vector_type(8))) short short8v;

__device__ __forceinline__ short f2bf(float f) {
  __hip_bfloat16 h = __float2bfloat16(f);  // RNE
  short s;
  __builtin_memcpy(&s, &h, 2);
  return s;
}

__device__ __forceinline__ float gelu_exact(float x) {
  return 0.5f * x * (1.f + erff(x * 0.70710678118654752f));
}

__device__ __forceinline__ float wave_sum64(float v) {
#pragma unroll
  for (int off = 32; off > 0; off >>= 1) v += __shfl_xor(v, off);
  return v;
}

// ---------------- router ----------------
__global__ __launch_bounds__(HID) void router1_kernel(
    const float* __restrict__ h_t, const float* __restrict__ e_task,
    const float* __restrict__ e_layout, const float* __restrict__ W1,
    const float* __restrict__ b1, const float* __restrict__ W2,
    const float* __restrict__ b2, const float* __restrict__ hintW,
    const float* __restrict__ hintb, float* __restrict__ gp_ws,
    float* __restrict__ gp_out) {
  int b = blockIdx.x;
  int t = threadIdx.x;
  float acc = b1[t];
  const float* rows[3] = {h_t + b * D, e_task + b * D, e_layout + b * D};
  for (int seg = 0; seg < 3; ++seg) {
    const float* r = rows[seg];
    const float* w = W1 + (size_t)seg * D * HID;
    for (int i = 0; i < D; ++i) acc += r[i] * w[i * HID + t];
  }
  __shared__ float hid[HID];
  __shared__ float logits[E];
  hid[t] = fmaxf(acc, 0.f);
  __syncthreads();
  if (t < E) {
    float l = b2[t] + hintb[t];
    for (int hh = 0; hh < HID; ++hh) l += hid[hh] * W2[hh * E + t];
    const float* el = e_layout + b * D;
    for (int dd = 0; dd < D; ++dd) l += el[dd] * hintW[dd * E + t];
    logits[t] = l;
  }
  __syncthreads();
  if (t == 0) {
    float mx = logits[0];
    for (int e2 = 1; e2 < E; ++e2) mx = fmaxf(mx, logits[e2]);
    float p[E];
    float se = 0.f;
    for (int e2 = 0; e2 < E; ++e2) {
      p[e2] = expf(logits[e2] - mx);
      se += p[e2];
    }
    float inv = 1.f / se;
    for (int e2 = 0; e2 < E; ++e2) {
      float pe = p[e2] * inv;
      gp_ws[b * E + e2] = pe;
      gp_out[b * E + e2] = pe;
    }
  }
}

__global__ __launch_bounds__(64) void router2_kernel(
    const float* __restrict__ gp, const int* __restrict__ topk_ptr,
    float* __restrict__ comb) {
  __shared__ int allk1;
  int t = threadIdx.x;
  if (t == 0) allk1 = 1;
  __syncthreads();
  float p[E];
  if (t < B) {
    float mx = 0.f;
    for (int e2 = 0; e2 < E; ++e2) {
      p[e2] = gp[t * E + e2];
      mx = fmaxf(mx, p[e2]);
    }
    if (!(mx > THRESH)) allk1 = 0;  // benign race: all writers store 0
  }
  __syncthreads();
  int k1 = allk1;
  if (t < B) {
    for (int e2 = 0; e2 < E; ++e2) comb[t * E + e2] = 0.f;
    int tk = *topk_ptr;
    if (tk > E) tk = E;
    float q[E];
    for (int e2 = 0; e2 < E; ++e2) q[e2] = p[e2];
    for (int kk = 0; kk < tk; ++kk) {
      int bi = 0;
      float bv = q[0];
      for (int e2 = 1; e2 < E; ++e2)
        if (q[e2] > bv) { bv = q[e2]; bi = e2; }
      float w = (kk == 0) ? bv : (k1 ? 0.f : bv);
      comb[t * E + bi] += w;
      q[bi] = -1.f;
    }
  }
}

// ---------------- embedding + LN (wave per row, expert in grid.y) ----------
__global__ __launch_bounds__(256) void embed_ln_w(
    const float* __restrict__ h_t, const float* __restrict__ e_task,
    const float* __restrict__ e_layout, const float* __restrict__ tok,
    const float* __restrict__ pos_b, const float* __restrict__ typ_b,
    const float* __restrict__ g_b, const float* __restrict__ bb_b,
    float* __restrict__ out_b, const float* __restrict__ comb) {
  int e = blockIdx.y;
  int t = threadIdx.x, lane = t & 63, w = t >> 6;
  int row = blockIdx.x * 4 + w;
  int b = row >> 7, s = row & 127;
  if (comb[b * E + e] == 0.f) return;
  const float* pos_e = pos_b + (size_t)e * MAXPOS * D;
  const float* typ_e = typ_b + (size_t)e * D;
  const float* g = g_b + (size_t)e * D;
  const float* bb = bb_b + (size_t)e * D;
  float* outp = out_b + (size_t)e * BSD;
  int d0 = lane * 4;
  const float* src = (s >= 3) ? tok + ((size_t)(b * N + s - 3)) * D
                   : (s == 0) ? h_t + (size_t)b * D
                   : (s == 1) ? e_task + (size_t)b * D
                              : e_layout + (size_t)b * D;
  float4 x = *reinterpret_cast<const float4*>(src + d0);
  float4 pe = *reinterpret_cast<const float4*>(pos_e + (size_t)s * D + d0);
  float4 te = *reinterpret_cast<const float4*>(typ_e + d0);
  x.x += pe.x + te.x; x.y += pe.y + te.y;
  x.z += pe.z + te.z; x.w += pe.w + te.w;
  float mean = wave_sum64(x.x + x.y + x.z + x.w) * (1.f / D);
  float4 xm = {x.x - mean, x.y - mean, x.z - mean, x.w - mean};
  float vv = wave_sum64(xm.x * xm.x + xm.y * xm.y + xm.z * xm.z + xm.w * xm.w);
  float rs = rsqrtf(vv * (1.f / D) + EPS);
  float4 g4 = *reinterpret_cast<const float4*>(g + d0);
  float4 b4 = *reinterpret_cast<const float4*>(bb + d0);
  float4 o = {xm.x * rs * g4.x + b4.x, xm.y * rs * g4.y + b4.y,
              xm.z * rs * g4.z + b4.z, xm.w * rs * g4.w + b4.w};
  *reinterpret_cast<float4*>(outp + (size_t)row * D + d0) = o;
}

// ---------------- add + LN (wave per row, expert in grid.y) ----------------
__global__ __launch_bounds__(256) void add_ln_w(
    const float* __restrict__ A_b, const float* __restrict__ R_b,
    const float* __restrict__ g_b, const float* __restrict__ bb_b,
    float* __restrict__ out_b, const float* __restrict__ comb) {
  int e = blockIdx.y;
  int t = threadIdx.x, lane = t & 63, w = t >> 6;
  int row = blockIdx.x * 4 + w;
  int b = row >> 7;
  if (comb[b * E + e] == 0.f) return;
  const float* A = A_b + (size_t)e * BSD;
  const float* R = R_b + (size_t)e * BSD;
  const float* g = g_b + (size_t)e * D;
  const float* bb = bb_b + (size_t)e * D;
  float* outp = out_b + (size_t)e * BSD;
  int d0 = lane * 4;
  float4 a4 = *reinterpret_cast<const float4*>(A + (size_t)row * D + d0);
  float4 r4 = *reinterpret_cast<const float4*>(R + (size_t)row * D + d0);
  float4 x = {a4.x + r4.x, a4.y + r4.y, a4.z + r4.z, a4.w + r4.w};
  float mean = wave_sum64(x.x + x.y + x.z + x.w) * (1.f / D);
  float4 xm = {x.x - mean, x.y - mean, x.z - mean, x.w - mean};
  float vv = wave_sum64(xm.x * xm.x + xm.y * xm.y + xm.z * xm.z + xm.w * xm.w);
  float rs = rsqrtf(vv * (1.f / D) + EPS);
  float4 g4 = *reinterpret_cast<const float4*>(g + d0);
  float4 b4 = *reinterpret_cast<const float4*>(bb + d0);
  float4 o = {xm.x * rs * g4.x + b4.x, xm.y * rs * g4.y + b4.y,
              xm.z * rs * g4.z + b4.z, xm.w * rs * g4.w + b4.w};
  *reinterpret_cast<float4*>(outp + (size_t)row * D + d0) = o;
}

// ---------------- attention: thread per query row, expert in grid.y --------
__global__ __launch_bounds__(128) void attn2_kernel(
    const float* __restrict__ Qb, const float* __restrict__ Kb,
    const float* __restrict__ Vb, float* __restrict__ Cb,
    const float* __restrict__ comb) {
  int e = blockIdx.y;
  int bh = blockIdx.x;
  int b = bh >> 3, h = bh & 7;
  if (comb[b * E + e] == 0.f) return;
  const float* Q = Qb + (size_t)e * BSD;
  const float* K = Kb + (size_t)e * BSD;
  const float* Vv = Vb + (size_t)e * BSD;
  float* C = Cb + (size_t)e * BSD;
  __shared__ float Ks[S][36];
  __shared__ float Vs[S][36];
  int t = threadIdx.x;
  const float* kb = K + ((size_t)(b * S + t)) * D + h * HD;
  const float* vb = Vv + ((size_t)(b * S + t)) * D + h * HD;
#pragma unroll
  for (int d = 0; d < HD; d += 4) {
    *reinterpret_cast<float4*>(&Ks[t][d]) =
        *reinterpret_cast<const float4*>(kb + d);
    *reinterpret_cast<float4*>(&Vs[t][d]) =
        *reinterpret_cast<const float4*>(vb + d);
  }
  float4 qv[8];
  const float* qp = Q + ((size_t)(b * S + t)) * D + h * HD;
#pragma unroll
  for (int j = 0; j < 8; ++j)
    qv[j] = *reinterpret_cast<const float4*>(qp + j * 4);
  __syncthreads();
  const float scale = 0.17677669529663687f;  // 1/sqrt(32)
  float mx = -1e30f;
  for (int k = 0; k < S; ++k) {
    float s = 0.f;
#pragma unroll
    for (int j = 0; j < 8; ++j) {
      float4 k4 = *reinterpret_cast<const float4*>(&Ks[k][j * 4]);
      s += qv[j].x * k4.x + qv[j].y * k4.y + qv[j].z * k4.z + qv[j].w * k4.w;
    }
    mx = fmaxf(mx, s * scale);
  }
  float se = 0.f;
  float4 cx[8];
#pragma unroll
  for (int j = 0; j < 8; ++j) cx[j] = {0.f, 0.f, 0.f, 0.f};
  for (int k = 0; k < S; ++k) {
    float s = 0.f;
#pragma unroll
    for (int j = 0; j < 8; ++j) {
      float4 k4 = *reinterpret_cast<const float4*>(&Ks[k][j * 4]);
      s += qv[j].x * k4.x + qv[j].y * k4.y + qv[j].z * k4.z + qv[j].w * k4.w;
    }
    float p = expf(s * scale - mx);
    se += p;
#pragma unroll
    for (int j = 0; j < 8; ++j) {
      float4 v4 = *reinterpret_cast<const float4*>(&Vs[k][j * 4]);
      cx[j].x += p * v4.x; cx[j].y += p * v4.y;
      cx[j].z += p * v4.z; cx[j].w += p * v4.w;
    }
  }
  float inv = 1.f / se;
  float* cp = C + ((size_t)(b * S + t)) * D + h * HD;
#pragma unroll
  for (int j = 0; j < 8; ++j) {
    float4 o = {cx[j].x * inv, cx[j].y * inv, cx[j].z * inv, cx[j].w * inv};
    *reinterpret_cast<float4*>(cp + j * 4) = o;
  }
}

// ---------------- shared bf16-MFMA GEMM tile body (128x128, BK=32) ---------
template <int ACT, int K, int Nc>
__device__ __forceinline__ void gemm_body(
    const float* __restrict__ Ag, const float* __restrict__ Wg,
    const float* __restrict__ bias, float* __restrict__ outp, int row0,
    int col0) {
  // padded stride 40 bf16 (80B): frag ds_read_b128 lands 2-way (free, m136)
  __shared__ short Al[128 * 40];
  __shared__ short Bl[128 * 40];
  const int t = threadIdx.x;
  const int lane = t & 63;
  const int w = t >> 6;
  const int wr = w >> 1, wc = w & 1;
  const int lrow = lane & 15;
  const int lkoff = (lane >> 4) * 8;  // bf16 units

  f32x4 acc[4][4];
#pragma unroll
  for (int m = 0; m < 4; ++m)
#pragma unroll
    for (int n = 0; n < 4; ++n) acc[m][n] = (f32x4){0.f, 0.f, 0.f, 0.f};

  const int colB = t >> 1, kh = (t & 1) * 16;
  for (int k0 = 0; k0 < K; k0 += 32) {
#pragma unroll
    for (int j = 0; j < 4; ++j) {
      int id = t + 256 * j;
      int row = id >> 3, s4 = id & 7;
      float4 a4 = *reinterpret_cast<const float4*>(
          Ag + (size_t)(row0 + row) * K + k0 + s4 * 4);
      short4 p;
      p.x = f2bf(a4.x); p.y = f2bf(a4.y); p.z = f2bf(a4.z); p.w = f2bf(a4.w);
      *reinterpret_cast<short4*>(&Al[row * 40 + s4 * 4]) = p;
    }
    {
      const float* wp = Wg + (size_t)(k0 + kh) * Nc + (col0 + colB);
      short8v v0, v1;
#pragma unroll
      for (int kk = 0; kk < 8; ++kk) v0[kk] = f2bf(wp[(size_t)kk * Nc]);
#pragma unroll
      for (int kk = 0; kk < 8; ++kk) v1[kk] = f2bf(wp[(size_t)(kk + 8) * Nc]);
      *reinterpret_cast<short8v*>(&Bl[colB * 40 + kh]) = v0;
      *reinterpret_cast<short8v*>(&Bl[colB * 40 + kh + 8]) = v1;
    }
    __syncthreads();
    short8v af[4], bfv[4];
#pragma unroll
    for (int m = 0; m < 4; ++m)
      af[m] = *reinterpret_cast<const short8v*>(
          &Al[(wr * 64 + m * 16 + lrow) * 40 + lkoff]);
#pragma unroll
    for (int n = 0; n < 4; ++n)
      bfv[n] = *reinterpret_cast<const short8v*>(
          &Bl[(wc * 64 + n * 16 + lrow) * 40 + lkoff]);
#pragma unroll
    for (int m = 0; m < 4; ++m)
#pragma unroll
      for (int n = 0; n < 4; ++n)
        acc[m][n] = __builtin_amdgcn_mfma_f32_16x16x32_bf16(
            af[m], bfv[n], acc[m][n], 0, 0, 0);
    __syncthreads();
  }
  // epilogue: C row = (lane>>4)*4 + reg, col = lane&15   [m89 layout]
#pragma unroll
  for (int n = 0; n < 4; ++n) {
    int col = col0 + wc * 64 + n * 16 + lrow;
    float bc = bias[col];
#pragma unroll
    for (int m = 0; m < 4; ++m) {
      int rbase = row0 + wr * 64 + m * 16 + (lane >> 4) * 4;
      f32x4 v = acc[m][n];
#pragma unroll
      for (int r = 0; r < 4; ++r) {
        float o = v[r] + bc;
        if (ACT == 1) o = gelu_exact(o);
        outp[(size_t)(rbase + r) * Nc + col] = o;
      }
    }
  }
}

// generic per-expert GEMM: A[e], W[e], bias[e] -> out[e]; grid (cols, rows, E)
template <int ACT, int K, int Nc>
__global__ __launch_bounds__(256) void gemm_e(
    const float* __restrict__ Ab, const float* __restrict__ Wb,
    const float* __restrict__ biasb, float* __restrict__ outb,
    const float* __restrict__ comb) {
  int e = blockIdx.z;
  int row0 = blockIdx.y * 128;
  int col0 = blockIdx.x * 128;
  int b = row0 >> 7;
  if (comb[b * E + e] == 0.f) return;
  gemm_body<ACT, K, Nc>(Ab + (size_t)e * B * S * K,
                        Wb + (size_t)e * K * Nc, biasb + (size_t)e * Nc,
                        outb + (size_t)e * B * S * Nc, row0, col0);
}

// fused QKV: blockIdx.x = which*2 + coltile
__global__ __launch_bounds__(256) void qkv_e(
    const float* __restrict__ h0b, const float* __restrict__ Wqb,
    const float* __restrict__ Wkb, const float* __restrict__ Wvb,
    const float* __restrict__ bqb, const float* __restrict__ bkb,
    const float* __restrict__ bvb, float* __restrict__ qb,
    float* __restrict__ kb, float* __restrict__ vb,
    const float* __restrict__ comb) {
  int e = blockIdx.z;
  int which = blockIdx.x >> 1;
  int col0 = (blockIdx.x & 1) * 128;
  int row0 = blockIdx.y * 128;
  int b = row0 >> 7;
  if (comb[b * E + e] == 0.f) return;
  const float* Wg = (which == 0 ? Wqb : which == 1 ? Wkb : Wvb) +
                    (size_t)e * D * D;
  const float* bias = (which == 0 ? bqb : which == 1 ? bkb : bvb) +
                      (size_t)e * D;
  float* outp = (which == 0 ? qb : which == 1 ? kb : vb) + (size_t)e * BSD;
  gemm_body<0, D, D>(h0b + (size_t)e * BSD, Wg, bias, outp, row0, col0);
}

// head GEMM: grid (rows=32, cols=250) — x-fastest dispatch keeps a W
// col-stripe resident across all 32 row tiles (fixes 1 GB W re-fetch).
__global__ __launch_bounds__(256) void head_gemm(
    const float* __restrict__ Ag, const float* __restrict__ Wg,
    const float* __restrict__ bias, float* __restrict__ outp) {
  int row0 = blockIdx.x * 128;
  int col0 = blockIdx.y * 128;
  gemm_body<0, D, V>(Ag, Wg, bias, outp, row0, col0);
}

// gated combine: z = sum_e comb[b,e] * h_fin[e]
__global__ __launch_bounds__(256) void combine_kernel(
    const float* __restrict__ hb, const float* __restrict__ comb,
    float* __restrict__ z) {
  size_t i = ((size_t)blockIdx.x * 256 + threadIdx.x) * 4;
  int b = (int)(i >> 15);  // / (S*D)
  float4 acc = {0.f, 0.f, 0.f, 0.f};
#pragma unroll
  for (int e2 = 0; e2 < E; ++e2) {
    float c = comb[b * E + e2];
    if (c != 0.f) {
      float4 v = *reinterpret_cast<const float4*>(hb + (size_t)e2 * BSD + i);
      acc.x += c * v.x; acc.y += c * v.y;
      acc.z += c * v.z; acc.w += c * v.w;
    }
  }
  *reinterpret_cast<float4*>(z + i) = acc;
}

}  // namespace

extern "C" void kernel_launch(void* const* d_in, const int* in_sizes, int n_in,
                              void* d_out, int out_size, void* d_ws,
                              size_t ws_size, hipStream_t stream) {
  const float* h_t = (const float*)d_in[0];
  const float* e_task = (const float*)d_in[1];
  const float* e_layout = (const float*)d_in[2];
  const float* tok = (const float*)d_in[3];
  const float* rW1 = (const float*)d_in[4];
  const float* rb1 = (const float*)d_in[5];
  const float* rW2 = (const float*)d_in[6];
  const float* rb2 = (const float*)d_in[7];
  const float* hW = (const float*)d_in[8];
  const float* hb = (const float*)d_in[9];
  const float* pos = (const float*)d_in[10];
  const float* typ = (const float*)d_in[11];
  const float* g0 = (const float*)d_in[12];
  const float* b0 = (const float*)d_in[13];
  const float* Wq = (const float*)d_in[14];
  const float* bq = (const float*)d_in[15];
  const float* Wk = (const float*)d_in[16];
  const float* bk = (const float*)d_in[17];
  const float* Wv = (const float*)d_in[18];
  const float* bv = (const float*)d_in[19];
  const float* Wo = (const float*)d_in[20];
  const float* bo = (const float*)d_in[21];
  const float* g1 = (const float*)d_in[22];
  const float* b1 = (const float*)d_in[23];
  const float* Wf1 = (const float*)d_in[24];
  const float* bf1 = (const float*)d_in[25];
  const float* Wf2 = (const float*)d_in[26];
  const float* bf2 = (const float*)d_in[27];
  const float* g2 = (const float*)d_in[28];
  const float* b2 = (const float*)d_in[29];
  const float* headW = (const float*)d_in[30];
  const float* headb = (const float*)d_in[31];
  const int* topk = (const int*)d_in[32];

  float* out = (float*)d_out;
  float* gp_out = out + (size_t)B * S * V;  // gate_probs tail of d_out

  // Per-expert scratch (expert dim = e*stride) in the logits region of d_out.
  // Total 188.7 MB < 524 MB region; all fully overwritten by head_gemm later.
  float* h0 = out;                        // [E][B*S, D]
  float* qb2 = h0 + (size_t)E * BSD;      // [E][B*S, D]
  float* kb2 = qb2 + (size_t)E * BSD;     // [E][B*S, D]
  float* vb2 = kb2 + (size_t)E * BSD;     // [E][B*S, D]
  float* ctxb = vb2 + (size_t)E * BSD;    // [E][B*S, D]
  float* fb = ctxb + (size_t)E * BSD;     // [E][B*S, FF]

  float* comb = (float*)d_ws;  // [B,E] padded
  float* gp = comb + 256;      // [B,E] padded
  float* zb = gp + 256;        // [B*S, D] fp32 (survives head GEMM)

  router1_kernel<<<B, HID, 0, stream>>>(h_t, e_task, e_layout, rW1, rb1, rW2,
                                        rb2, hW, hb, gp, gp_out);
  router2_kernel<<<1, 64, 0, stream>>>(gp, topk, comb);

  dim3 gLN(B * S / 4, E);
  embed_ln_w<<<gLN, 256, 0, stream>>>(h_t, e_task, e_layout, tok, pos, typ,
                                      g0, b0, h0, comb);
  qkv_e<<<dim3(6, 32, E), 256, 0, stream>>>(h0, Wq, Wk, Wv, bq, bk, bv, qb2,
                                            kb2, vb2, comb);
  attn2_kernel<<<dim3(B * H, E), 128, 0, stream>>>(qb2, kb2, vb2, ctxb, comb);
  gemm_e<0, D, D><<<dim3(2, 32, E), 256, 0, stream>>>(ctxb, Wo, bo, qb2, comb);
  add_ln_w<<<gLN, 256, 0, stream>>>(h0, qb2, g1, b1, kb2, comb);
  gemm_e<1, D, FF><<<dim3(8, 32, E), 256, 0, stream>>>(kb2, Wf1, bf1, fb,
                                                       comb);
  gemm_e<0, FF, D><<<dim3(2, 32, E), 256, 0, stream>>>(fb, Wf2, bf2, vb2,
                                                       comb);
  add_ln_w<<<gLN, 256, 0, stream>>>(kb2, vb2, g2, b2, h0, comb);
  combine_kernel<<<BSD / 1024, 256, 0, stream>>>(h0, comb, zb);

  head_gemm<<<dim3(32, V / 128), 256, 0, stream>>>(zb, headW, headb, out);
  (void)in_sizes; (void)n_in; (void)out_size; (void)ws_size;
}